// Round 6
// baseline (201.681 us; speedup 1.0000x reference)
//
#include <hip/hip_runtime.h>
#include <math.h>

#define KW 65
#define L_LEN 65536
#define B_N 32
#define OC_N 64
#define KPAD 160      // two 80-wide channel sections
#define SEC 80
#define LT 256        // l per tile
#define NT 8          // tiles per block
#define LGRP (LT*NT)  // 2048 l per block
#define XBASE 344     // staged window length in shorts (mult of 8)

typedef __attribute__((ext_vector_type(8))) short short8;
typedef __attribute__((ext_vector_type(4))) float f32x4;
typedef __attribute__((ext_vector_type(4))) unsigned u32x4;

__device__ __forceinline__ unsigned short f2bf(float f) {
    unsigned u = __builtin_bit_cast(unsigned, f);
    unsigned r = u + 0x7FFFu + ((u >> 16) & 1u);
    return (unsigned short)(r >> 16);
}

__device__ __forceinline__ float nan0(float v) {
    if (isnan(v)) return 0.0f;
    if (isinf(v)) return v > 0.0f ? 3.4028234663852886e38f : -3.4028234663852886e38f;
    return v;
}

// ---------------- Kernel A: steered weights, packed bf16 [B][OC][160] -------
__global__ __launch_bounds__(256) void steer_weights(
        const int* __restrict__ z, const float* __restrict__ s,
        const float* __restrict__ bw, unsigned short* __restrict__ wpk) {
    const float PI = 3.14159265358979323846f;
    const float FS = 50000000.0f;
    int b = blockIdx.x;
    int t = threadIdx.x;

    const int*   zb = z + b * 5;
    const float* sb = s + b * 5;
    float f0    = (zb[0] > 0) ? nan0(sb[0]) : 0.0f;
    float alpha = (zb[1] > 0) ? nan0(sb[1]) : 1.0f;
    float gain  = (zb[2] > 0) ? nan0(sb[2]) : 1.0f;
    float shf   = (zb[3] > 0) ? nan0(sb[3]) : 0.0f;
    float chirp = (zb[4] > 0) ? nan0(sb[4]) : 0.0f;

    float a = fmaxf(alpha, 0.001f);
    float Nf_raw = rintf(65.0f / a);          // jnp.round = half-to-even
    int   N  = (int)fminf(fmaxf(Nf_raw, 1.0f), 130.0f);
    float Nf = (float)N;
    int   sh = (int)rintf(shf);

    __shared__ float rw[OC_N][2][KW];
    __shared__ float cph[KW], sph[KW];
    __shared__ int   j0t[KW], j1t[KW];
    __shared__ float w2t[KW];
    __shared__ int   i0t[130], i1t[130];
    __shared__ float w1t[130];

    // coefficient tables (depend only on N) + phase table, all in parallel
    if (t < KW) {
        float n  = (float)t;
        float tt = n / FS;
        float phi = 2.0f * PI * f0 * n / FS + PI * chirp * tt * tt;
        cph[t] = cosf(phi);
        sph[t] = sinf(phi);
        float c2  = fmaxf(((float)t + 0.5f) * (Nf / 65.0f) - 0.5f, 0.0f);
        float j0f = floorf(c2);
        j0t[t] = (int)j0f;
        j1t[t] = min((int)j0f + 1, N - 1);
        w2t[t] = c2 - j0f;
    } else if (t < KW + 130) {
        int j = t - KW;
        float c   = fmaxf(((float)j + 0.5f) * (65.0f / Nf) - 0.5f, 0.0f);
        float i0f = floorf(c);
        int   i0  = min((int)i0f, KW - 1);
        i0t[j] = i0;
        i1t[j] = min(i0 + 1, KW - 1);
        w1t[j] = c - i0f;
    }
    __syncthreads();

    // resample: 128 rows x 65 taps as table-lookup lerps
    for (int item = t; item < 128 * KW; item += 256) {
        int row = item / KW, i = item % KW;     // row = oc*2 + ch
        const float* w = bw + row * KW;
        int j0 = j0t[i], j1 = j1t[i];
        float v0 = (1.0f - w1t[j0]) * w[i0t[j0]] + w1t[j0] * w[i1t[j0]];
        float v1 = (1.0f - w1t[j1]) * w[i0t[j1]] + w1t[j1] * w[i1t[j1]];
        rw[row >> 1][row & 1][i] = (1.0f - w2t[i]) * v0 + w2t[i] * v1;
    }
    __syncthreads();

    // mix + gain + shift + pack: 4 threads per oc
    {
        int oc = t >> 2, q = t & 3;
        unsigned short* ob = wpk + ((size_t)b * OC_N + oc) * KPAD;
        int sh0 = ((sh % KW) + KW) % KW;
        int k0 = 17 * q, k1 = min(KW, k0 + 17);
        for (int k = k0; k < k1; ++k) {
            float I = rw[oc][0][k], Q = rw[oc][1][k];
            float cp = cph[k], sp = sph[k];
            float Ip = (I * cp - Q * sp) * gain;
            float Qp = (I * sp + Q * cp) * gain;
            int kk = k + sh0; if (kk >= KW) kk -= KW;
            ob[kk]       = f2bf(Ip);
            ob[SEC + kk] = f2bf(Qp);
        }
        if (q == 3) {
            for (int kk = KW; kk < SEC; ++kk) { ob[kk] = 0; ob[SEC + kk] = 0; }
        }
    }
}

// ---------------- Kernel B: implicit-GEMM conv via bf16 MFMA -----------------
// Block: 64 oc x 2048 l (8 tiles of 256), 4 waves (oc-half x l-half per tile).
// SINGLE bf16 x-copy per tile (double-buffered, 2.75 KB). All 8 MFMA phase
// fragments for a (s,c,g) live in one aligned 16-short window: 2 ds_read_b128
// + in-register v_alignbit funnel shifts replace the 8x phase-copy build.
// One __syncthreads per tile (proven semantics; R5's raw-barrier raced).
__global__ __launch_bounds__(256, 3) void steer_conv_mfma(
        const float* __restrict__ x, const unsigned short* __restrict__ wpk,
        float* __restrict__ y) {
    int b   = blockIdx.y;
    int L0  = blockIdx.x * LGRP;
    int tid = threadIdx.x;
    int wv = tid >> 6, lane = tid & 63;
    int c = lane & 15, g = lane >> 4;
    int a = wv & 1, lsub = wv >> 1;

    __shared__ __align__(16) unsigned short xt[2][2][XBASE];  // 2.75 KB

    // A fragments (weights) loaded once per block
    short8 afr[2][5];
    #pragma unroll
    for (int ot = 0; ot < 2; ++ot) {
        const unsigned short* wb = wpk + ((size_t)b * OC_N + 32 * a + 16 * ot + c) * KPAD;
        #pragma unroll
        for (int s = 0; s < 5; ++s)
            afr[ot][s] = *(const short8*)(wb + 32 * s + 8 * g);
    }

    const float* xb = x + (size_t)b * 2 * L_LEN;

    bool isLdr = (tid < 172);
    int lch = tid / 86, li4 = tid % 86;   // valid when isLdr

    // per-lane base of the 16-short fragment window (shorts, 8-aligned)
    int boff[5];
    #pragma unroll
    for (int s = 0; s < 5; ++s) {
        int k0 = 32 * s + 8 * g;
        int ch = (k0 >= SEC) ? 1 : 0;
        int t0 = k0 - SEC * ch;
        boff[s] = ch * XBASE + 128 * lsub + 8 * c + t0;   // *2B -> 16B aligned
    }

    auto loadwin = [&](int l0) -> float4 {
        int gi = l0 - 32 + 4 * li4;
        float4 v;
        if (gi >= 0 && gi + 3 < L_LEN) {
            v = *(const float4*)(xb + (size_t)lch * L_LEN + gi);
        } else {
            float tmp[4];
            #pragma unroll
            for (int u = 0; u < 4; ++u) {
                int q = gi + u;
                tmp[u] = (q >= 0 && q < L_LEN) ? xb[(size_t)lch * L_LEN + q] : 0.0f;
            }
            v = make_float4(tmp[0], tmp[1], tmp[2], tmp[3]);
        }
        return v;
    };

    float4 v = make_float4(0.f, 0.f, 0.f, 0.f);
    if (isLdr) v = loadwin(L0);

    int cur = 0;
    for (int t = 0; t < NT; ++t) {
        int l0 = L0 + t * LT;
        // stage bf16 copy of tile t's window
        if (isLdr) {
            unsigned r0 = (unsigned)f2bf(v.x) | ((unsigned)f2bf(v.y) << 16);
            unsigned r1 = (unsigned)f2bf(v.z) | ((unsigned)f2bf(v.w) << 16);
            *(uint2*)&xt[cur][lch][4 * li4] = make_uint2(r0, r1);
        }
        __syncthreads();

        // issue next tile's global loads; latency hides under MFMA+stores
        float4 vN = v;
        if (isLdr && t + 1 < NT) vN = loadwin(l0 + LT);

        f32x4 acc[2][8];
        #pragma unroll
        for (int ot = 0; ot < 2; ++ot)
            #pragma unroll
            for (int p = 0; p < 8; ++p) acc[ot][p] = (f32x4){0.f, 0.f, 0.f, 0.f};

        const unsigned short* xs = &xt[cur][0][0];
        #pragma unroll
        for (int s = 0; s < 5; ++s) {
            const uint4* w16 = (const uint4*)(xs + boff[s]);
            uint4 q0 = w16[0], q1 = w16[1];
            unsigned d[8] = { q0.x, q0.y, q0.z, q0.w, q1.x, q1.y, q1.z, q1.w };
            #pragma unroll
            for (int p = 0; p < 8; ++p) {
                u32x4 ov;
                if (p & 1) {
                    int q = p >> 1;
                    ov = (u32x4){ (d[q]     >> 16) | (d[q + 1] << 16),
                                  (d[q + 1] >> 16) | (d[q + 2] << 16),
                                  (d[q + 2] >> 16) | (d[q + 3] << 16),
                                  (d[q + 3] >> 16) | (d[q + 4] << 16) };
                } else {
                    int q = p >> 1;
                    ov = (u32x4){ d[q], d[q + 1], d[q + 2], d[q + 3] };
                }
                short8 bfr = __builtin_bit_cast(short8, ov);
                acc[0][p] = __builtin_amdgcn_mfma_f32_16x16x32_bf16(afr[0][s], bfr, acc[0][p], 0, 0, 0);
                acc[1][p] = __builtin_amdgcn_mfma_f32_16x16x32_bf16(afr[1][s], bfr, acc[1][p], 0, 0, 0);
            }
        }

        // store: lane holds 8 contiguous l per (ot, r): l = l0+128*lsub+8c+p
        #pragma unroll
        for (int ot = 0; ot < 2; ++ot) {
            #pragma unroll
            for (int r = 0; r < 4; ++r) {
                int oc = 32 * a + 16 * ot + 4 * g + r;
                float* yr = y + ((size_t)b * OC_N + oc) * L_LEN + l0 + 128 * lsub + 8 * c;
                f32x4 lo = { acc[ot][0][r], acc[ot][1][r], acc[ot][2][r], acc[ot][3][r] };
                f32x4 hi = { acc[ot][4][r], acc[ot][5][r], acc[ot][6][r], acc[ot][7][r] };
                *(f32x4*)yr       = lo;
                *((f32x4*)yr + 1) = hi;
            }
        }
        v = vN;
        cur ^= 1;
    }
}

extern "C" void kernel_launch(void* const* d_in, const int* in_sizes, int n_in,
                              void* d_out, int out_size, void* d_ws, size_t ws_size,
                              hipStream_t stream) {
    const float* x  = (const float*)d_in[0];
    const int*   z  = (const int*)d_in[1];
    const float* s  = (const float*)d_in[2];
    const float* bw = (const float*)d_in[3];
    float* y = (float*)d_out;
    unsigned short* wpk = (unsigned short*)d_ws;   // 32*64*160*2 = 655 KB

    steer_weights<<<dim3(B_N), dim3(256), 0, stream>>>(z, s, bw, wpk);
    steer_conv_mfma<<<dim3(L_LEN / LGRP, B_N), dim3(256), 0, stream>>>(x, wpk, y);
}

// Round 7
// 177.668 us; speedup vs baseline: 1.1352x; 1.1352x over previous
//
#include <hip/hip_runtime.h>
#include <math.h>

#define KW 65
#define L_LEN 65536
#define B_N 32
#define OC_N 64
#define OCPB 16       // oc per block
#define KPAD 160      // two 80-wide channel sections
#define SEC 80
#define LT 512        // l per tile
#define NT 16         // tiles per block
#define LGRP (LT*NT)  // 8192 l per block
#define XSTG 592      // staged phase-0 shorts per channel (148 float4)
#define XW 600        // allocated row length (shorts)

typedef __attribute__((ext_vector_type(8))) short short8;
typedef __attribute__((ext_vector_type(4))) float f32x4;

__device__ __forceinline__ unsigned short f2bf(float f) {
    unsigned u = __builtin_bit_cast(unsigned, f);
    unsigned r = u + 0x7FFFu + ((u >> 16) & 1u);
    return (unsigned short)(r >> 16);
}

__device__ __forceinline__ float nan0(float v) {
    if (isnan(v)) return 0.0f;
    if (isinf(v)) return v > 0.0f ? 3.4028234663852886e38f : -3.4028234663852886e38f;
    return v;
}

// ---------------- Kernel A: steered weights, packed bf16 [B][OC][160] -------
__global__ __launch_bounds__(256) void steer_weights(
        const int* __restrict__ z, const float* __restrict__ s,
        const float* __restrict__ bw, unsigned short* __restrict__ wpk) {
    const float PI = 3.14159265358979323846f;
    const float FS = 50000000.0f;
    int b = blockIdx.x;
    int t = threadIdx.x;

    const int*   zb = z + b * 5;
    const float* sb = s + b * 5;
    float f0    = (zb[0] > 0) ? nan0(sb[0]) : 0.0f;
    float alpha = (zb[1] > 0) ? nan0(sb[1]) : 1.0f;
    float gain  = (zb[2] > 0) ? nan0(sb[2]) : 1.0f;
    float shf   = (zb[3] > 0) ? nan0(sb[3]) : 0.0f;
    float chirp = (zb[4] > 0) ? nan0(sb[4]) : 0.0f;

    float a = fmaxf(alpha, 0.001f);
    float Nf_raw = rintf(65.0f / a);          // jnp.round = half-to-even
    int   N  = (int)fminf(fmaxf(Nf_raw, 1.0f), 130.0f);
    float Nf = (float)N;
    int   sh = (int)rintf(shf);

    __shared__ float rw[OC_N][2][KW];
    __shared__ float cph[KW], sph[KW];
    __shared__ int   j0t[KW], j1t[KW];
    __shared__ float w2t[KW];
    __shared__ int   i0t[130], i1t[130];
    __shared__ float w1t[130];

    // coefficient tables (depend only on N) + phase table, all in parallel
    if (t < KW) {
        float n  = (float)t;
        float tt = n / FS;
        float phi = 2.0f * PI * f0 * n / FS + PI * chirp * tt * tt;
        cph[t] = cosf(phi);
        sph[t] = sinf(phi);
        float c2  = fmaxf(((float)t + 0.5f) * (Nf / 65.0f) - 0.5f, 0.0f);
        float j0f = floorf(c2);
        j0t[t] = (int)j0f;
        j1t[t] = min((int)j0f + 1, N - 1);
        w2t[t] = c2 - j0f;
    } else if (t < KW + 130) {
        int j = t - KW;
        float c   = fmaxf(((float)j + 0.5f) * (65.0f / Nf) - 0.5f, 0.0f);
        float i0f = floorf(c);
        int   i0  = min((int)i0f, KW - 1);
        i0t[j] = i0;
        i1t[j] = min(i0 + 1, KW - 1);
        w1t[j] = c - i0f;
    }
    __syncthreads();

    // resample: 128 rows x 65 taps as table-lookup lerps
    for (int item = t; item < 128 * KW; item += 256) {
        int row = item / KW, i = item % KW;     // row = oc*2 + ch
        const float* w = bw + row * KW;
        int j0 = j0t[i], j1 = j1t[i];
        float v0 = (1.0f - w1t[j0]) * w[i0t[j0]] + w1t[j0] * w[i1t[j0]];
        float v1 = (1.0f - w1t[j1]) * w[i0t[j1]] + w1t[j1] * w[i1t[j1]];
        rw[row >> 1][row & 1][i] = (1.0f - w2t[i]) * v0 + w2t[i] * v1;
    }
    __syncthreads();

    // mix + gain + shift + pack: 4 threads per oc
    {
        int oc = t >> 2, q = t & 3;
        unsigned short* ob = wpk + ((size_t)b * OC_N + oc) * KPAD;
        int sh0 = ((sh % KW) + KW) % KW;
        int k0 = 17 * q, k1 = min(KW, k0 + 17);
        for (int k = k0; k < k1; ++k) {
            float I = rw[oc][0][k], Q = rw[oc][1][k];
            float cp = cph[k], sp = sph[k];
            float Ip = (I * cp - Q * sp) * gain;
            float Qp = (I * sp + Q * cp) * gain;
            int kk = k + sh0; if (kk >= KW) kk -= KW;
            ob[kk]       = f2bf(Ip);
            ob[SEC + kk] = f2bf(Qp);
        }
        if (q == 3) {
            for (int kk = KW; kk < SEC; ++kk) { ob[kk] = 0; ob[SEC + kk] = 0; }
        }
    }
}

// ---------------- Kernel B: implicit-GEMM conv via bf16 MFMA -----------------
// Block: 16 oc x 8192 l (16 tiles of 512). 4 waves = l-slices of 128.
// Per tile each of the 16 y-rows receives one 2KB contiguous segment, appended
// sequentially across 16 tiles (32KB/row/block) -> consolidated HBM write
// streams (64/CU vs 192/CU before). R4's proven 2-barrier, 8-phase-copy,
// double-buffered structure otherwise unchanged.
__global__ __launch_bounds__(256, 4) void steer_conv_mfma(
        const float* __restrict__ x, const unsigned short* __restrict__ wpk,
        float* __restrict__ y) {
    int b   = blockIdx.z;
    int ocb = blockIdx.y;
    int L0  = blockIdx.x * LGRP;
    int tid = threadIdx.x;
    int wv = tid >> 6, lane = tid & 63;
    int c = lane & 15, g = lane >> 4;

    __shared__ __align__(16) unsigned short xt[2][8][2][XW];  // 37.5 KB

    // A fragments (weights) for this block's 16 oc, loaded once
    const unsigned short* wb = wpk + ((size_t)b * OC_N + ocb * OCPB + c) * KPAD;
    short8 afr[5];
    #pragma unroll
    for (int s = 0; s < 5; ++s)
        afr[s] = *(const short8*)(wb + 32 * s + 8 * g);

    const float* xb = x + (size_t)b * 2 * L_LEN;

    // stage mapping: item in [0,296): ch = item/148, i4 = item%148
    auto loadwin = [&](int l0, int item) -> float4 {
        int ch = item / 148, i4 = item % 148;
        int gi = l0 - 32 + 4 * i4;
        float4 v;
        if (gi >= 0 && gi + 3 < L_LEN) {
            v = *(const float4*)(xb + (size_t)ch * L_LEN + gi);
        } else {
            float tmp[4];
            #pragma unroll
            for (int u = 0; u < 4; ++u) {
                int q = gi + u;
                tmp[u] = (q >= 0 && q < L_LEN) ? xb[(size_t)ch * L_LEN + q] : 0.0f;
            }
            v = make_float4(tmp[0], tmp[1], tmp[2], tmp[3]);
        }
        return v;
    };

    // per-lane B-fragment offsets (shorts) within one phase copy
    int boff[5];
    #pragma unroll
    for (int s = 0; s < 5; ++s) {
        int k0 = 32 * s + 8 * g;
        int ch = (k0 >= SEC) ? 1 : 0;
        int t0 = k0 - SEC * ch;
        boff[s] = ch * XW + 128 * wv + 8 * c + t0;   // *2B -> 16B aligned
    }

    float4 v0 = loadwin(L0, tid);
    float4 v1 = make_float4(0.f, 0.f, 0.f, 0.f);
    if (tid < 40) v1 = loadwin(L0, tid + 256);

    int cur = 0;
    for (int t = 0; t < NT; ++t) {
        int l0 = L0 + t * LT;
        // stage bf16 phase-0 copy of tile t's window
        {
            int ch = tid / 148, i4 = tid % 148;
            unsigned r0 = (unsigned)f2bf(v0.x) | ((unsigned)f2bf(v0.y) << 16);
            unsigned r1 = (unsigned)f2bf(v0.z) | ((unsigned)f2bf(v0.w) << 16);
            *(uint2*)&xt[cur][0][ch][4 * i4] = make_uint2(r0, r1);
            if (tid < 40) {
                int item = tid + 256;
                int ch2 = item / 148, j4 = item % 148;
                unsigned q0 = (unsigned)f2bf(v1.x) | ((unsigned)f2bf(v1.y) << 16);
                unsigned q1 = (unsigned)f2bf(v1.z) | ((unsigned)f2bf(v1.w) << 16);
                *(uint2*)&xt[cur][0][ch2][4 * j4] = make_uint2(q0, q1);
            }
        }
        __syncthreads();

        // issue next tile's global loads (latency hides under build+MFMA)
        if (t + 1 < NT) {
            v0 = loadwin(l0 + LT, tid);
            if (tid < 40) v1 = loadwin(l0 + LT, tid + 256);
        }

        // build phases 1..7 by 16-bit funnel shifts (one d-read per (ch,j))
        if (tid < 146) {
            int ch = tid / 73, j = tid % 73;
            const uint4* srcq = (const uint4*)&xt[cur][0][ch][8 * j];
            uint4 q0 = srcq[0], q1 = srcq[1];
            unsigned d[8] = { q0.x, q0.y, q0.z, q0.w, q1.x, q1.y, q1.z, q1.w };
            #pragma unroll
            for (int p = 1; p < 8; ++p) {
                int q = p >> 1;
                unsigned o[4];
                #pragma unroll
                for (int i = 0; i < 4; ++i)
                    o[i] = (p & 1) ? ((d[i + q] >> 16) | (d[i + q + 1] << 16)) : d[i + q];
                *(uint4*)&xt[cur][p][ch][8 * j] = make_uint4(o[0], o[1], o[2], o[3]);
            }
        }
        __syncthreads();

        f32x4 acc[8];
        #pragma unroll
        for (int p = 0; p < 8; ++p) acc[p] = (f32x4){0.f, 0.f, 0.f, 0.f};

        const unsigned short* xs = &xt[cur][0][0][0];
        #pragma unroll
        for (int s = 0; s < 5; ++s) {
            #pragma unroll
            for (int p = 0; p < 8; ++p) {
                short8 bfr = *(const short8*)(xs + p * 2 * XW + boff[s]);
                acc[p] = __builtin_amdgcn_mfma_f32_16x16x32_bf16(afr[s], bfr, acc[p], 0, 0, 0);
            }
        }

        // store: lane holds 8 contiguous l per r: l = l0 + 128*wv + 8c + p
        #pragma unroll
        for (int r = 0; r < 4; ++r) {
            int oc = ocb * OCPB + 4 * g + r;
            float* yr = y + ((size_t)b * OC_N + oc) * L_LEN + l0 + 128 * wv + 8 * c;
            f32x4 lo = { acc[0][r], acc[1][r], acc[2][r], acc[3][r] };
            f32x4 hi = { acc[4][r], acc[5][r], acc[6][r], acc[7][r] };
            *(f32x4*)yr       = lo;
            *((f32x4*)yr + 1) = hi;
        }
        cur ^= 1;
    }
}

extern "C" void kernel_launch(void* const* d_in, const int* in_sizes, int n_in,
                              void* d_out, int out_size, void* d_ws, size_t ws_size,
                              hipStream_t stream) {
    const float* x  = (const float*)d_in[0];
    const int*   z  = (const int*)d_in[1];
    const float* s  = (const float*)d_in[2];
    const float* bw = (const float*)d_in[3];
    float* y = (float*)d_out;
    unsigned short* wpk = (unsigned short*)d_ws;   // 32*64*160*2 = 655 KB

    steer_weights<<<dim3(B_N), dim3(256), 0, stream>>>(z, s, bw, wpk);
    steer_conv_mfma<<<dim3(L_LEN / LGRP, OC_N / OCPB, B_N), dim3(256), 0, stream>>>(x, wpk, y);
}

// Round 8
// 153.102 us; speedup vs baseline: 1.3173x; 1.1605x over previous
//
#include <hip/hip_runtime.h>
#include <math.h>

#define KW 65
#define L_LEN 65536
#define B_N 32
#define OC_N 64
#define KPAD 160      // two 80-wide channel sections
#define SEC 80
#define LT 256        // l per tile
#define NT 8          // tiles per block
#define LGRP (LT*NT)  // 2048 l per block
#define XBASE 344     // base (phase-0) window length in shorts, mult of 8

typedef __attribute__((ext_vector_type(8))) short short8;
typedef __attribute__((ext_vector_type(4))) float f32x4;

__device__ __forceinline__ unsigned short f2bf(float f) {
    unsigned u = __builtin_bit_cast(unsigned, f);
    unsigned r = u + 0x7FFFu + ((u >> 16) & 1u);
    return (unsigned short)(r >> 16);
}

__device__ __forceinline__ float nan0(float v) {
    if (isnan(v)) return 0.0f;
    if (isinf(v)) return v > 0.0f ? 3.4028234663852886e38f : -3.4028234663852886e38f;
    return v;
}

// LDS-only workgroup barrier: rendezvous + LDS ordering, but does NOT drain
// vmcnt — y-stores and prefetch loads stay in flight across tiles (T4).
// IR-level fences (not inline asm) so the compiler cannot reorder LDS ops
// across it (no rule-#18 hazard).
__device__ __forceinline__ void barrier_lds() {
    __builtin_amdgcn_fence(__ATOMIC_RELEASE, "workgroup", "local");
    __builtin_amdgcn_s_barrier();
    __builtin_amdgcn_fence(__ATOMIC_ACQUIRE, "workgroup", "local");
}

// ---------------- Kernel A: steered weights, packed bf16 [B][OC][160] -------
__global__ __launch_bounds__(256) void steer_weights(
        const int* __restrict__ z, const float* __restrict__ s,
        const float* __restrict__ bw, unsigned short* __restrict__ wpk) {
    const float PI = 3.14159265358979323846f;
    const float FS = 50000000.0f;
    int b = blockIdx.x;
    int t = threadIdx.x;

    const int*   zb = z + b * 5;
    const float* sb = s + b * 5;
    float f0    = (zb[0] > 0) ? nan0(sb[0]) : 0.0f;
    float alpha = (zb[1] > 0) ? nan0(sb[1]) : 1.0f;
    float gain  = (zb[2] > 0) ? nan0(sb[2]) : 1.0f;
    float shf   = (zb[3] > 0) ? nan0(sb[3]) : 0.0f;
    float chirp = (zb[4] > 0) ? nan0(sb[4]) : 0.0f;

    float a = fmaxf(alpha, 0.001f);
    float Nf_raw = rintf(65.0f / a);          // jnp.round = half-to-even
    int   N  = (int)fminf(fmaxf(Nf_raw, 1.0f), 130.0f);
    float Nf = (float)N;
    int   sh = (int)rintf(shf);

    __shared__ float rw[OC_N][2][KW];
    __shared__ float cph[KW], sph[KW];
    __shared__ int   j0t[KW], j1t[KW];
    __shared__ float w2t[KW];
    __shared__ int   i0t[130], i1t[130];
    __shared__ float w1t[130];

    // coefficient tables (depend only on N) + phase table, all in parallel
    if (t < KW) {
        float n  = (float)t;
        float tt = n / FS;
        float phi = 2.0f * PI * f0 * n / FS + PI * chirp * tt * tt;
        cph[t] = cosf(phi);
        sph[t] = sinf(phi);
        float c2  = fmaxf(((float)t + 0.5f) * (Nf / 65.0f) - 0.5f, 0.0f);
        float j0f = floorf(c2);
        j0t[t] = (int)j0f;
        j1t[t] = min((int)j0f + 1, N - 1);
        w2t[t] = c2 - j0f;
    } else if (t < KW + 130) {
        int j = t - KW;
        float c   = fmaxf(((float)j + 0.5f) * (65.0f / Nf) - 0.5f, 0.0f);
        float i0f = floorf(c);
        int   i0  = min((int)i0f, KW - 1);
        i0t[j] = i0;
        i1t[j] = min(i0 + 1, KW - 1);
        w1t[j] = c - i0f;
    }
    __syncthreads();

    // resample: 128 rows x 65 taps as table-lookup lerps
    for (int item = t; item < 128 * KW; item += 256) {
        int row = item / KW, i = item % KW;     // row = oc*2 + ch
        const float* w = bw + row * KW;
        int j0 = j0t[i], j1 = j1t[i];
        float v0 = (1.0f - w1t[j0]) * w[i0t[j0]] + w1t[j0] * w[i1t[j0]];
        float v1 = (1.0f - w1t[j1]) * w[i0t[j1]] + w1t[j1] * w[i1t[j1]];
        rw[row >> 1][row & 1][i] = (1.0f - w2t[i]) * v0 + w2t[i] * v1;
    }
    __syncthreads();

    // mix + gain + shift + pack: 4 threads per oc
    {
        int oc = t >> 2, q = t & 3;
        unsigned short* ob = wpk + ((size_t)b * OC_N + oc) * KPAD;
        int sh0 = ((sh % KW) + KW) % KW;
        int k0 = 17 * q, k1 = min(KW, k0 + 17);
        for (int k = k0; k < k1; ++k) {
            float I = rw[oc][0][k], Q = rw[oc][1][k];
            float cp = cph[k], sp = sph[k];
            float Ip = (I * cp - Q * sp) * gain;
            float Qp = (I * sp + Q * cp) * gain;
            int kk = k + sh0; if (kk >= KW) kk -= KW;
            ob[kk]       = f2bf(Ip);
            ob[SEC + kk] = f2bf(Qp);
        }
        if (q == 3) {
            for (int kk = KW; kk < SEC; ++kk) { ob[kk] = 0; ob[SEC + kk] = 0; }
        }
    }
}

// ---------------- Kernel B: implicit-GEMM conv via bf16 MFMA -----------------
// R4 structure verbatim (64 oc x 2048 l per block, 8 tiles of 256, 4 waves,
// double-buffered 8-phase LDS copies, 2 barriers/tile) with ONE change:
// barriers are LDS-only (no vmcnt(0) drain) so y-stores from tile t overlap
// tile t+1's stage/build/MFMA. Clean A/B against R4's 142.2 us.
__global__ __launch_bounds__(256, 3) void steer_conv_mfma(
        const float* __restrict__ x, const unsigned short* __restrict__ wpk,
        float* __restrict__ y) {
    int b   = blockIdx.y;
    int L0  = blockIdx.x * LGRP;
    int tid = threadIdx.x;
    int wv = tid >> 6, lane = tid & 63;
    int c = lane & 15, g = lane >> 4;
    int a = wv & 1, lsub = wv >> 1;

    __shared__ __align__(16) unsigned short xt[2][8][2][XBASE];  // 22 KB

    // A fragments (weights) loaded once per block
    short8 afr[2][5];
    #pragma unroll
    for (int ot = 0; ot < 2; ++ot) {
        const unsigned short* wb = wpk + ((size_t)b * OC_N + 32 * a + 16 * ot + c) * KPAD;
        #pragma unroll
        for (int s = 0; s < 5; ++s)
            afr[ot][s] = *(const short8*)(wb + 32 * s + 8 * g);
    }

    const float* xb = x + (size_t)b * 2 * L_LEN;

    bool isLoader = (tid >= 84);
    int lidx = tid - 84;
    int lch = lidx / 86, li4 = lidx % 86;

    // per-lane B-fragment element offsets (shorts) within a phase copy
    int boff[5];
    #pragma unroll
    for (int s = 0; s < 5; ++s) {
        int k0 = 32 * s + 8 * g;
        int ch = (k0 >= SEC) ? 1 : 0;
        int t0 = k0 - SEC * ch;
        boff[s] = ch * XBASE + 128 * lsub + 8 * c + t0;   // *2B -> 16B aligned
    }

    auto loadwin = [&](int l0) -> float4 {
        int gi = l0 - 32 + 4 * li4;
        float4 v;
        if (gi >= 0 && gi + 3 < L_LEN) {
            v = *(const float4*)(xb + (size_t)lch * L_LEN + gi);
        } else {
            float tmp[4];
            #pragma unroll
            for (int u = 0; u < 4; ++u) {
                int q = gi + u;
                tmp[u] = (q >= 0 && q < L_LEN) ? xb[(size_t)lch * L_LEN + q] : 0.0f;
            }
            v = make_float4(tmp[0], tmp[1], tmp[2], tmp[3]);
        }
        return v;
    };

    float4 v = make_float4(0.f, 0.f, 0.f, 0.f);
    if (isLoader) v = loadwin(L0);

    int cur = 0;
    for (int t = 0; t < NT; ++t) {
        int l0 = L0 + t * LT;
        // write bf16 base copy (phase 0) of tile t
        if (isLoader) {
            unsigned r0 = (unsigned)f2bf(v.x) | ((unsigned)f2bf(v.y) << 16);
            unsigned r1 = (unsigned)f2bf(v.z) | ((unsigned)f2bf(v.w) << 16);
            *(uint2*)&xt[cur][0][lch][4 * li4] = make_uint2(r0, r1);
        }
        barrier_lds();
        if (tid < 84) {
            // build phases 1..7 by 16-bit funnel shifts of the base copy
            int ch = tid / 42, j = tid % 42;
            const unsigned* src = (const unsigned*)&xt[cur][0][ch][8 * j];
            unsigned d[8];
            #pragma unroll
            for (int i = 0; i < 8; ++i) d[i] = src[i];
            #pragma unroll
            for (int p = 1; p < 8; ++p) {
                int q = p >> 1;
                unsigned o[4];
                #pragma unroll
                for (int i = 0; i < 4; ++i)
                    o[i] = (p & 1) ? ((d[i + q] >> 16) | (d[i + q + 1] << 16)) : d[i + q];
                *(uint4*)&xt[cur][p][ch][8 * j] = make_uint4(o[0], o[1], o[2], o[3]);
            }
        } else if (t + 1 < NT) {
            // prefetch next tile's window into registers
            int gi = L0 + (t + 1) * LT - 32 + 4 * li4;
            if (gi >= 0 && gi + 3 < L_LEN) {
                v = loadwin(l0 + LT);
            } else {
                v = loadwin(l0 + LT);
            }
        }
        barrier_lds();

        f32x4 acc[2][8];
        #pragma unroll
        for (int ot = 0; ot < 2; ++ot)
            #pragma unroll
            for (int p = 0; p < 8; ++p) acc[ot][p] = (f32x4){0.f, 0.f, 0.f, 0.f};

        #pragma unroll
        for (int p = 0; p < 8; ++p) {
            const unsigned short* xp = &xt[cur][p][0][0];
            #pragma unroll
            for (int s = 0; s < 5; ++s) {
                short8 bfr = *(const short8*)(xp + boff[s]);
                acc[0][p] = __builtin_amdgcn_mfma_f32_16x16x32_bf16(afr[0][s], bfr, acc[0][p], 0, 0, 0);
                acc[1][p] = __builtin_amdgcn_mfma_f32_16x16x32_bf16(afr[1][s], bfr, acc[1][p], 0, 0, 0);
            }
        }

        // store: lane holds 8 contiguous l per (ot, r): l = l0+128*lsub+8c+p
        #pragma unroll
        for (int ot = 0; ot < 2; ++ot) {
            #pragma unroll
            for (int r = 0; r < 4; ++r) {
                int oc = 32 * a + 16 * ot + 4 * g + r;
                float* yr = y + ((size_t)b * OC_N + oc) * L_LEN + l0 + 128 * lsub + 8 * c;
                f32x4 lo = { acc[ot][0][r], acc[ot][1][r], acc[ot][2][r], acc[ot][3][r] };
                f32x4 hi = { acc[ot][4][r], acc[ot][5][r], acc[ot][6][r], acc[ot][7][r] };
                *(f32x4*)yr       = lo;
                *((f32x4*)yr + 1) = hi;
            }
        }
        cur ^= 1;
    }
}

extern "C" void kernel_launch(void* const* d_in, const int* in_sizes, int n_in,
                              void* d_out, int out_size, void* d_ws, size_t ws_size,
                              hipStream_t stream) {
    const float* x  = (const float*)d_in[0];
    const int*   z  = (const int*)d_in[1];
    const float* s  = (const float*)d_in[2];
    const float* bw = (const float*)d_in[3];
    float* y = (float*)d_out;
    unsigned short* wpk = (unsigned short*)d_ws;   // 32*64*160*2 = 655 KB

    steer_weights<<<dim3(B_N), dim3(256), 0, stream>>>(z, s, bw, wpk);
    steer_conv_mfma<<<dim3(L_LEN / LGRP, B_N), dim3(256), 0, stream>>>(x, wpk, y);
}